// Round 4
// baseline (274.880 us; speedup 1.0000x reference)
//
#include <hip/hip_runtime.h>
#include <math.h>

#define NCAM 6
#define FHh 16
#define FWw 44
#define PIX 704            // FHh*FWw
#define FCc 128
#define DB 48
#define C3 177             // DB + 1 + 128
#define C3PAD 192
#define KCONV 1152         // FCc*9
#define NG 4224            // NCAM*PIX
#define BEVN 10000
#define NTILE 100          // 10x10 tiles of 10x10 BEV pixels

// ---- ws layout (float offsets) ----
#define OFF_WT1    0
#define OFF_WT2    147456
#define OFF_WT3    294912                      // [128][192] zero-padded
#define OFF_GEO    319488                      // [6*48*704][2] (x,y only)
#define OFF_X1     724992                      // [6][128][704]
#define OFF_X2     1265664
#define OFF_X3     1806336                     // [6][177][704]
#define OFF_PRM    2553984                     // SoA [10][NG]: py,px,qc,qa,qb,op,ymin,ymax,xmin,xmax
#define OFF_FEATT  2596224                     // [NG][128]
#define OFF_PART   3136896                     // [4][6][128][704] gemm partials
#define OFF_TLIST  3136896                     // alias PART: [100][4224] ints
#define OFF_TCNT   3559296                     // [100] ints
// end = 5,299,584 floats = 20.2 MiB

__device__ __forceinline__ void inv3(const float* A, float* I) {
  float a=A[0],b=A[1],c=A[2],d=A[3],e=A[4],f=A[5],g=A[6],h=A[7],i=A[8];
  float c0 = e*i - f*h, c1 = f*g - d*i, c2 = d*h - e*g;
  float det = a*c0 + b*c1 + c*c2;
  float id = 1.f/det;
  I[0]=c0*id; I[1]=(c*h-b*i)*id; I[2]=(b*f-c*e)*id;
  I[3]=c1*id; I[4]=(a*i-c*g)*id; I[5]=(c*d-a*f)*id;
  I[6]=c2*id; I[7]=(b*g-a*h)*id; I[8]=(a*e-b*d)*id;
}

// fused prep + geometry: per-block redundant 3x3 inverses in LDS
__global__ void k_geom(const float* __restrict__ rot, const float* __restrict__ intr,
                       const float* __restrict__ post_rot,
                       const float* __restrict__ trans, const float* __restrict__ post_trans,
                       float* __restrict__ ws) {
  __shared__ float sm[NCAM][24];
  if (threadIdx.x < NCAM) {
    int n = threadIdx.x;
    float ip[9], ii[9];
    inv3(post_rot + n*9, ip);
    inv3(intr + n*9, ii);
    const float* R = rot + n*9;
    for (int j = 0; j < 9; ++j) sm[n][j] = ip[j];
    for (int r = 0; r < 3; ++r)
      for (int c = 0; c < 3; ++c) {
        float s = 0.f;
        for (int k = 0; k < 3; ++k) s += R[r*3+k]*ii[k*3+c];
        sm[n][9 + r*3 + c] = s;
      }
  }
  __syncthreads();
  int idx = blockIdx.x*256 + threadIdx.x;
  if (idx >= NCAM*DB*PIX) return;
  int n = idx / (DB*PIX);
  int rem = idx % (DB*PIX);
  int d = rem / PIX;
  int hw = rem % PIX;
  int h = hw / FWw, w = hw % FWw;
  float fx = w * (351.0f/43.0f);
  float fy = h * (127.0f/15.0f);
  float fz = 1.0f + (float)d;
  const float* pt = post_trans + n*3;
  float v0 = fx - pt[0], v1 = fy - pt[1], v2 = fz - pt[2];
  const float* m = sm[n];
  float x = m[0]*v0 + m[1]*v1 + m[2]*v2;
  float y = m[3]*v0 + m[4]*v1 + m[5]*v2;
  float z = m[6]*v0 + m[7]*v1 + m[8]*v2;
  float q0 = x*z, q1 = y*z, q2 = z;
  const float* c = m + 9;
  const float* t = trans + n*3;
  float gx = c[0]*q0 + c[1]*q1 + c[2]*q2 + t[0];
  float gy = c[3]*q0 + c[4]*q1 + c[5]*q2 + t[1];
  ((float2*)(ws + OFF_GEO))[idx] = make_float2(gx, gy);
}

__global__ void k_wtrans(const float* __restrict__ w1, const float* __restrict__ w2,
                         const float* __restrict__ w3, float* __restrict__ ws) {
  int e = blockIdx.x*256 + threadIdx.x;
  if (e < 147456) {
    int k = e / FCc, oc = e % FCc;           // wT[k][oc]
    ws[OFF_WT1 + e] = w1[oc*KCONV + k];
    ws[OFF_WT2 + e] = w2[oc*KCONV + k];
  }
  if (e < 128*C3PAD) {
    int k = e / C3PAD, oc = e % C3PAD;
    ws[OFF_WT3 + e] = (oc < C3) ? w3[oc*FCc + k] : 0.f;
  }
}

// im2col GEMM. If bias != null (KSPLIT==1): write final [n][oc_limit][704] with bias.
__global__ __launch_bounds__(256) void k_gemm(
    const float* __restrict__ in,    // [6][128][16][44]
    const float* __restrict__ wT,    // [K][Mpad]
    float* __restrict__ part,
    const float* __restrict__ bias, float* __restrict__ outbuf, int oc_limit,
    int Mpad, int KH, int PAD, int KSPLIT, int Kchunk)
{
  __shared__ float la[16][64];
  __shared__ float lb[16][64];
  int tid = threadIdx.x;
  int oc0 = blockIdx.x * 64;
  int px0 = blockIdx.y * 64;
  int z = blockIdx.z;
  int n = z / KSPLIT, ks = z % KSPLIT;
  int KK = KH*KH;
  int k0 = ks * Kchunk;
  int r   = tid >> 4;          // 0..15
  int col = (tid & 15) << 2;   // 0..60
  const float* inn = in + (size_t)n*FCc*PIX;
  int yb[4], xb[4];
  #pragma unroll
  for (int i = 0; i < 4; ++i) {
    int p = px0 + col + i;
    yb[i] = p / FWw; xb[i] = p - yb[i]*FWw;
  }
  float acc[4][4] = {};
  int steps = Kchunk >> 4;
  for (int s = 0; s < steps; ++s) {
    int kbase = k0 + (s << 4);
    float4 av = *(const float4*)&wT[(size_t)(kbase + r)*Mpad + oc0 + col];
    *(float4*)&la[r][col] = av;
    int k = kbase + r;
    int ic = k / KK;
    int rr = k - ic*KK;
    int ky = rr / KH, kx = rr - ky*KH;
    const float* ip = inn + (size_t)ic*PIX;
    #pragma unroll
    for (int i = 0; i < 4; ++i) {
      int yy = yb[i] + ky - PAD, xx = xb[i] + kx - PAD;
      float v = 0.f;
      if ((unsigned)yy < FHh && (unsigned)xx < FWw) v = ip[yy*FWw + xx];
      lb[r][col + i] = v;
    }
    __syncthreads();
    #pragma unroll
    for (int kk = 0; kk < 16; ++kk) {
      float4 a4 = *(const float4*)&la[kk][r << 2];
      float4 b4 = *(const float4*)&lb[kk][col];
      acc[0][0] += a4.x*b4.x; acc[0][1] += a4.x*b4.y; acc[0][2] += a4.x*b4.z; acc[0][3] += a4.x*b4.w;
      acc[1][0] += a4.y*b4.x; acc[1][1] += a4.y*b4.y; acc[1][2] += a4.y*b4.z; acc[1][3] += a4.y*b4.w;
      acc[2][0] += a4.z*b4.x; acc[2][1] += a4.z*b4.y; acc[2][2] += a4.z*b4.z; acc[2][3] += a4.z*b4.w;
      acc[3][0] += a4.w*b4.x; acc[3][1] += a4.w*b4.y; acc[3][2] += a4.w*b4.z; acc[3][3] += a4.w*b4.w;
    }
    __syncthreads();
  }
  if (bias) {
    #pragma unroll
    for (int i = 0; i < 4; ++i) {
      int oc = oc0 + (r<<2) + i;
      if (oc < oc_limit) {
        float b = bias[oc];
        float4 st = make_float4(acc[i][0]+b, acc[i][1]+b, acc[i][2]+b, acc[i][3]+b);
        *(float4*)&outbuf[(size_t)(n*oc_limit + oc)*PIX + px0 + col] = st;
      }
    }
  } else {
    float* pp = part + (size_t)(ks*NCAM + n)*Mpad*PIX;
    #pragma unroll
    for (int i = 0; i < 4; ++i) {
      float4 st = make_float4(acc[i][0], acc[i][1], acc[i][2], acc[i][3]);
      *(float4*)&pp[(size_t)(oc0 + (r<<2) + i)*PIX + px0 + col] = st;
    }
  }
}

__global__ void k_epi_bn(const float* __restrict__ part, const float* __restrict__ cb,
                         const float* __restrict__ g, const float* __restrict__ be,
                         const float* __restrict__ mn, const float* __restrict__ vr,
                         float* __restrict__ out, int KSPLIT)
{
  int idx = blockIdx.x*256 + threadIdx.x;       // float4 over [6][128][176]
  if (idx >= NCAM*FCc*176) return;
  int px4 = idx % 176;
  int t = idx / 176;
  int oc = t % FCc;
  int n = t / FCc;
  float4 s = {0.f,0.f,0.f,0.f};
  for (int ks = 0; ks < KSPLIT; ++ks) {
    const float4* p = (const float4*)(part + (size_t)((ks*NCAM+n)*FCc + oc)*PIX);
    float4 v = p[px4];
    s.x += v.x; s.y += v.y; s.z += v.z; s.w += v.w;
  }
  float inv = g[oc] * rsqrtf(vr[oc] + 1e-3f);
  float sh = (cb[oc] - mn[oc]) * inv + be[oc];
  float4 o;
  o.x = fmaxf(s.x*inv + sh, 0.f);
  o.y = fmaxf(s.y*inv + sh, 0.f);
  o.z = fmaxf(s.z*inv + sh, 0.f);
  o.w = fmaxf(s.w*inv + sh, 0.f);
  ((float4*)(out + (size_t)(n*FCc + oc)*PIX))[px4] = o;
}

// one wave per gaussian: softmax over depth, moments, raster params + bbox, feat transpose
__global__ void k_moments(float* __restrict__ ws) {
  int wid  = (blockIdx.x * 256 + threadIdx.x) >> 6;
  int lane = threadIdx.x & 63;
  int n = wid / PIX, hw = wid % PIX;
  const float* x3 = ws + OFF_X3 + (size_t)n*C3*PIX + hw;
  float logit = (lane < DB) ? x3[(size_t)lane*PIX] : -1e30f;
  float mx = logit;
  for (int off = 1; off < 64; off <<= 1) mx = fmaxf(mx, __shfl_xor(mx, off));
  float e = (lane < DB) ? expf(logit - mx) : 0.f;
  float s = e;
  for (int off = 1; off < 64; off <<= 1) s += __shfl_xor(s, off);
  float p = e / s;
  float gx = 0.f, gy = 0.f;
  if (lane < DB) {
    float2 g2 = ((const float2*)(ws + OFF_GEO))[(size_t)(n*DB + lane)*PIX + hw];
    gx = g2.x; gy = g2.y;
  }
  float sx = p*gx;
  for (int off = 1; off < 64; off <<= 1) sx += __shfl_xor(sx, off);
  float sy = p*gy;
  for (int off = 1; off < 64; off <<= 1) sy += __shfl_xor(sy, off);
  float dx = gx - sx, dy = gy - sy;
  float c00 = p*dx*dx, c01 = p*dx*dy, c11 = p*dy*dy;
  for (int off = 1; off < 64; off <<= 1) c00 += __shfl_xor(c00, off);
  for (int off = 1; off < 64; off <<= 1) c01 += __shfl_xor(c01, off);
  for (int off = 1; off < 64; off <<= 1) c11 += __shfl_xor(c11, off);
  float opl = x3[(size_t)DB*PIX];
  float opac = 1.f / (1.f + expf(-opl));
  // cov*(1/9) * scale^2(4e-4) * (sh*sw = 2500) => cov/9 in BEV cells, +0.3 dilate
  float a = c11*(1.f/9.f) + 0.3f;   // var along py
  float b = c01*(1.f/9.f);
  float c = c00*(1.f/9.f) + 0.3f;   // var along px
  float py = 50.f - sy;
  float px = 50.f - sx;
  float det = a*c - b*b;
  float op = (opac > 0.05f) ? opac : 0.f;
  float invd = 1.f;
  if (det > 0.f) invd = 1.f/det; else op = 0.f;
  float* prm = ws + OFF_PRM;
  if (lane == 0) {
    prm[0*NG + wid] = py;
    prm[1*NG + wid] = px;
    prm[2*NG + wid] = -0.5f*c*invd;  // dy^2 coeff
    prm[3*NG + wid] = -0.5f*a*invd;  // dx^2 coeff
    prm[4*NG + wid] = b*invd;        // dy*dx coeff
    prm[5*NG + wid] = op;
    float ymin = 1e9f, ymax = -1e9f, xmin = 1e9f, xmax = -1e9f;
    if (op > 0.f) {
      float L = logf(256.f*op);      // support bound for alpha >= 1/255 (small margin)
      float ry = sqrtf(2.f*L*a);
      float rx = sqrtf(2.f*L*c);
      ymin = py - ry; ymax = py + ry;
      xmin = px - rx; xmax = px + rx;
    }
    prm[6*NG + wid] = ymin;
    prm[7*NG + wid] = ymax;
    prm[8*NG + wid] = xmin;
    prm[9*NG + wid] = xmax;
  }
  float* ft = ws + OFF_FEATT + (size_t)wid*128;
  ft[lane]      = x3[(size_t)(DB + 1 + lane)*PIX];
  ft[lane + 64] = x3[(size_t)(DB + 1 + lane + 64)*PIX];
}

// order-preserving binning: one block per 10x10 BEV tile
__global__ __launch_bounds__(256) void k_bin(float* __restrict__ ws) {
  int t = blockIdx.x;
  int ty = t / 10, tx = t % 10;
  float y0 = (float)(ty*10), y1 = y0 + 9.f;
  float x0 = (float)(tx*10), x1 = x0 + 9.f;
  const float* prm = ws + OFF_PRM;
  int* list = (int*)(ws + OFF_TLIST) + t*NG;
  __shared__ int cnt4[4];
  int tid = threadIdx.x;
  int wv = tid >> 6, lane = tid & 63;
  int base = 0;
  for (int g0 = 0; g0 < NG; g0 += 256) {
    int g = g0 + tid;
    bool hit = false;
    if (g < NG) {
      float ymin = prm[6*NG + g], ymax = prm[7*NG + g];
      float xmin = prm[8*NG + g], xmax = prm[9*NG + g];
      hit = (ymin <= y1) && (ymax >= y0) && (xmin <= x1) && (xmax >= x0);
    }
    unsigned long long m = __ballot(hit);
    if (lane == 0) cnt4[wv] = __popcll(m);
    __syncthreads();
    int off = base;
    for (int w = 0; w < 4; ++w) if (w < wv) off += cnt4[w];
    off += __popcll(m & ((1ull << lane) - 1ull));
    if (hit) list[off] = g;
    base += cnt4[0] + cnt4[1] + cnt4[2] + cnt4[3];
    __syncthreads();
  }
  if (tid == 0) ((int*)(ws + OFF_TCNT))[t] = base;
}

// Segmented raster: block = 8 pixels of one tile; 8 waves each own a
// CONTIGUOUS 1/8 chunk of the tile list (composite is associative:
// F = F0 + P0*F1 + P0*P1*F2 ...). No barriers in main loop; one barrier
// before the ordered 8-step combine in LDS.
__global__ __launch_bounds__(512) void k_raster(const float* __restrict__ ws,
                                                float* __restrict__ out) {
  __shared__ float sF[8][8][128];   // [chunk][pixel][ch]
  __shared__ float sP[8][8];        // [chunk][pixel]
  int tid = threadIdx.x, lane = tid & 63, wv = tid >> 6;
  int t = blockIdx.x / 13, sub = blockIdx.x % 13;
  int ty = t / 10, tx = t % 10;
  float pyv[8], pxv[8];
  #pragma unroll
  for (int j = 0; j < 8; ++j) {
    int q = sub*8 + j; if (q > 99) q = 99;
    pyv[j] = (float)(ty*10 + q/10);
    pxv[j] = (float)(tx*10 + q%10);
  }
  const int* list = (const int*)(ws + OFF_TLIST) + t*NG;
  int cnt = ((const int*)(ws + OFF_TCNT))[t];
  const float* prm = ws + OFF_PRM;
  const float2* ft = (const float2*)(ws + OFF_FEATT);
  int nseg = (cnt + 63) >> 6;
  int gpc  = (nseg + 7) >> 3;
  int s0 = wv * gpc;
  int s1 = min(s0 + gpc, nseg);

  float Tp[8], ax[8], ay[8];
  #pragma unroll
  for (int j = 0; j < 8; ++j) { Tp[j] = 1.f; ax[j] = 0.f; ay[j] = 0.f; }

  // software pipeline: params(s) in regs, list(s+1) in reg
  int gcur = -1;
  float c_py=0.f,c_px=0.f,c_qc=0.f,c_qa=0.f,c_qb=0.f,c_op=0.f;
  if (s0 < s1) {
    int i0 = s0*64 + lane;
    gcur = (i0 < cnt) ? list[i0] : -1;
    if (gcur >= 0) {
      c_py = prm[0*NG+gcur]; c_px = prm[1*NG+gcur];
      c_qc = prm[2*NG+gcur]; c_qa = prm[3*NG+gcur];
      c_qb = prm[4*NG+gcur]; c_op = prm[5*NG+gcur];
    }
  }
  int gnxt = -1;
  if (s0 + 1 < s1) { int i1 = (s0+1)*64 + lane; gnxt = (i1 < cnt) ? list[i1] : -1; }

  for (int s = s0; s < s1; ++s) {
    // prefetch next group's params + the list entry after that
    int gn = gnxt;
    float n_py=0.f,n_px=0.f,n_qc=0.f,n_qa=0.f,n_qb=0.f,n_op=0.f;
    if (gn >= 0) {
      n_py = prm[0*NG+gn]; n_px = prm[1*NG+gn];
      n_qc = prm[2*NG+gn]; n_qa = prm[3*NG+gn];
      n_qb = prm[4*NG+gn]; n_op = prm[5*NG+gn];
    }
    int g2 = -1;
    if (s + 2 < s1) { int i2 = (s+2)*64 + lane; g2 = (i2 < cnt) ? list[i2] : -1; }

    #pragma unroll
    for (int j = 0; j < 8; ++j) {
      float dyv = c_py - pyv[j], dxv = c_px - pxv[j];
      float pw = c_qc*dyv*dyv + c_qa*dxv*dxv + c_qb*dyv*dxv;
      float alpha = c_op * __expf(fminf(pw, 0.f));
      alpha = fminf(alpha, 0.99f);
      if (alpha < (1.f/255.f)) alpha = 0.f;
      unsigned long long m0 = __ballot(alpha > 0.f);
      if (m0 && Tp[j] > 1e-7f) {          // wave-uniform (Tp is lane-uniform)
        float P = 1.f - alpha;
        #pragma unroll
        for (int off = 1; off < 64; off <<= 1) {
          float v = __shfl_up(P, off);
          if (lane >= off) P *= v;
        }
        float E = __shfl_up(P, 1);
        if (lane == 0) E = 1.f;
        float w = alpha * Tp[j] * E;      // alpha * exclusive local transmittance
        Tp[j] *= __shfl(P, 63);
        unsigned long long mask = __ballot(w > 1e-9f);
        while (mask) {
          int jj = __builtin_ctzll(mask);
          mask &= mask - 1;
          float wj = __shfl(w, jj);
          int gg = __shfl(gcur, jj);
          float2 f = ft[(size_t)gg*64 + lane];
          ax[j] += wj * f.x; ay[j] += wj * f.y;
        }
      }
    }
    gcur = gn;
    c_py=n_py; c_px=n_px; c_qc=n_qc; c_qa=n_qa; c_qb=n_qb; c_op=n_op;
    gnxt = g2;
    bool anyT = (Tp[0]>1e-7f)||(Tp[1]>1e-7f)||(Tp[2]>1e-7f)||(Tp[3]>1e-7f)
             || (Tp[4]>1e-7f)||(Tp[5]>1e-7f)||(Tp[6]>1e-7f)||(Tp[7]>1e-7f);
    if (!anyT) break;                     // chunk-local exit (error < 1e-7)
  }

  // write partials
  #pragma unroll
  for (int j = 0; j < 8; ++j) {
    sF[wv][j][2*lane]   = ax[j];
    sF[wv][j][2*lane+1] = ay[j];
    if (lane == 0) sP[wv][j] = Tp[j];
  }
  __syncthreads();
  // wave wv combines pixel wv in chunk order, result back into sF[0][wv]
  {
    int j = wv;
    float T = 1.f, fx = 0.f, fy = 0.f;
    #pragma unroll
    for (int s = 0; s < 8; ++s) {
      fx += T * sF[s][j][2*lane];
      fy += T * sF[s][j][2*lane+1];
      T *= sP[s][j];
    }
    sF[0][j][2*lane]   = fx;   // own-row write; other waves read other j rows
    sF[0][j][2*lane+1] = fy;
  }
  __syncthreads();
  // cooperative store: consecutive tids cover the 8 pixels within a channel
  for (int v = tid; v < 1024; v += 512) {
    int ch = v >> 3, j = v & 7;
    int q = sub*8 + j;
    if (q < 100) {
      int pix = (ty*10 + q/10)*100 + (tx*10 + q%10);
      out[(size_t)ch*BEVN + pix] = sF[0][j][ch];
    }
  }
}

extern "C" void kernel_launch(void* const* d_in, const int* in_sizes, int n_in,
                              void* d_out, int out_size, void* d_ws, size_t ws_size,
                              hipStream_t stream) {
  const float* rot        = (const float*)d_in[0];
  const float* trans      = (const float*)d_in[1];
  const float* intr       = (const float*)d_in[2];
  const float* post_rot   = (const float*)d_in[3];
  const float* post_trans = (const float*)d_in[4];
  const float* img        = (const float*)d_in[5];
  const float* w1  = (const float*)d_in[6];
  const float* b1  = (const float*)d_in[7];
  const float* g1  = (const float*)d_in[8];
  const float* be1 = (const float*)d_in[9];
  const float* m1  = (const float*)d_in[10];
  const float* v1  = (const float*)d_in[11];
  const float* w2  = (const float*)d_in[12];
  const float* b2  = (const float*)d_in[13];
  const float* g2  = (const float*)d_in[14];
  const float* be2 = (const float*)d_in[15];
  const float* m2  = (const float*)d_in[16];
  const float* v2  = (const float*)d_in[17];
  const float* w3  = (const float*)d_in[18];
  const float* b3  = (const float*)d_in[19];
  float* ws  = (float*)d_ws;
  float* out = (float*)d_out;

  k_wtrans<<<576, 256, 0, stream>>>(w1, w2, w3, ws);
  k_geom<<<792, 256, 0, stream>>>(rot, intr, post_rot, trans, post_trans, ws);

  // conv1: K=1152, KSPLIT=4
  k_gemm<<<dim3(2,11,24), 256, 0, stream>>>(img, ws+OFF_WT1, ws+OFF_PART,
                                            nullptr, nullptr, 0, 128, 3, 1, 4, 288);
  k_epi_bn<<<528, 256, 0, stream>>>(ws+OFF_PART, b1, g1, be1, m1, v1, ws+OFF_X1, 4);
  // conv2
  k_gemm<<<dim3(2,11,24), 256, 0, stream>>>(ws+OFF_X1, ws+OFF_WT2, ws+OFF_PART,
                                            nullptr, nullptr, 0, 128, 3, 1, 4, 288);
  k_epi_bn<<<528, 256, 0, stream>>>(ws+OFF_PART, b2, g2, be2, m2, v2, ws+OFF_X2, 4);
  // conv3: 1x1, K=128, bias fused, direct write to X3
  k_gemm<<<dim3(3,11,6), 256, 0, stream>>>(ws+OFF_X2, ws+OFF_WT3, ws+OFF_PART,
                                           b3, ws+OFF_X3, C3, 192, 1, 0, 1, 128);

  k_moments<<<1056, 256, 0, stream>>>(ws);
  k_bin<<<100, 256, 0, stream>>>(ws);
  k_raster<<<1300, 512, 0, stream>>>(ws, out);
}

// Round 5
// 210.169 us; speedup vs baseline: 1.3079x; 1.3079x over previous
//
#include <hip/hip_runtime.h>
#include <math.h>

#define NCAM 6
#define FHh 16
#define FWw 44
#define PIX 704            // FHh*FWw
#define FCc 128
#define DB 48
#define C3 177             // DB + 1 + 128
#define C3PAD 192
#define KCONV 1152         // FCc*9
#define NG 4224            // NCAM*PIX
#define BEVN 10000

// ---- ws layout (float offsets) ----
#define OFF_WT1    0
#define OFF_WT2    147456
#define OFF_WT3    294912                      // [128][192] zero-padded
#define OFF_GEO    319488                      // [6*48*704][2] (x,y only)
#define OFF_X1     724992                      // [6][128][704]
#define OFF_X2     1265664
#define OFF_X3     1806336                     // [6][177][704]
#define OFF_PRM    2553984                     // SoA [6][NG]: py,px,qc,qa,qb,op
#define OFF_FEATT  2579328                     // [NG][128]
#define OFF_PART   3120000                     // [4][6][128][704] gemm partials
// end = 5,282,688 floats = 20.2 MiB

__device__ __forceinline__ void inv3(const float* A, float* I) {
  float a=A[0],b=A[1],c=A[2],d=A[3],e=A[4],f=A[5],g=A[6],h=A[7],i=A[8];
  float c0 = e*i - f*h, c1 = f*g - d*i, c2 = d*h - e*g;
  float det = a*c0 + b*c1 + c*c2;
  float id = 1.f/det;
  I[0]=c0*id; I[1]=(c*h-b*i)*id; I[2]=(b*f-c*e)*id;
  I[3]=c1*id; I[4]=(a*i-c*g)*id; I[5]=(c*d-a*f)*id;
  I[6]=c2*id; I[7]=(b*g-a*h)*id; I[8]=(a*e-b*d)*id;
}

// fused prep + geometry: per-block redundant 3x3 inverses in LDS
__global__ void k_geom(const float* __restrict__ rot, const float* __restrict__ intr,
                       const float* __restrict__ post_rot,
                       const float* __restrict__ trans, const float* __restrict__ post_trans,
                       float* __restrict__ ws) {
  __shared__ float sm[NCAM][24];
  if (threadIdx.x < NCAM) {
    int n = threadIdx.x;
    float ip[9], ii[9];
    inv3(post_rot + n*9, ip);
    inv3(intr + n*9, ii);
    const float* R = rot + n*9;
    for (int j = 0; j < 9; ++j) sm[n][j] = ip[j];
    for (int r = 0; r < 3; ++r)
      for (int c = 0; c < 3; ++c) {
        float s = 0.f;
        for (int k = 0; k < 3; ++k) s += R[r*3+k]*ii[k*3+c];
        sm[n][9 + r*3 + c] = s;
      }
  }
  __syncthreads();
  int idx = blockIdx.x*256 + threadIdx.x;
  if (idx >= NCAM*DB*PIX) return;
  int n = idx / (DB*PIX);
  int rem = idx % (DB*PIX);
  int d = rem / PIX;
  int hw = rem % PIX;
  int h = hw / FWw, w = hw % FWw;
  float fx = w * (351.0f/43.0f);
  float fy = h * (127.0f/15.0f);
  float fz = 1.0f + (float)d;
  const float* pt = post_trans + n*3;
  float v0 = fx - pt[0], v1 = fy - pt[1], v2 = fz - pt[2];
  const float* m = sm[n];
  float x = m[0]*v0 + m[1]*v1 + m[2]*v2;
  float y = m[3]*v0 + m[4]*v1 + m[5]*v2;
  float z = m[6]*v0 + m[7]*v1 + m[8]*v2;
  float q0 = x*z, q1 = y*z, q2 = z;
  const float* c = m + 9;
  const float* t = trans + n*3;
  float gx = c[0]*q0 + c[1]*q1 + c[2]*q2 + t[0];
  float gy = c[3]*q0 + c[4]*q1 + c[5]*q2 + t[1];
  ((float2*)(ws + OFF_GEO))[idx] = make_float2(gx, gy);
}

__global__ void k_wtrans(const float* __restrict__ w1, const float* __restrict__ w2,
                         const float* __restrict__ w3, float* __restrict__ ws) {
  int e = blockIdx.x*256 + threadIdx.x;
  if (e < 147456) {
    int k = e / FCc, oc = e % FCc;           // wT[k][oc]
    ws[OFF_WT1 + e] = w1[oc*KCONV + k];
    ws[OFF_WT2 + e] = w2[oc*KCONV + k];
  }
  if (e < 128*C3PAD) {
    int k = e / C3PAD, oc = e % C3PAD;
    ws[OFF_WT3 + e] = (oc < C3) ? w3[oc*FCc + k] : 0.f;
  }
}

// im2col GEMM. If bias != null (KSPLIT==1): write final [n][oc_limit][704] with bias.
__global__ __launch_bounds__(256) void k_gemm(
    const float* __restrict__ in,    // [6][128][16][44]
    const float* __restrict__ wT,    // [K][Mpad]
    float* __restrict__ part,
    const float* __restrict__ bias, float* __restrict__ outbuf, int oc_limit,
    int Mpad, int KH, int PAD, int KSPLIT, int Kchunk)
{
  __shared__ float la[16][64];
  __shared__ float lb[16][64];
  int tid = threadIdx.x;
  int oc0 = blockIdx.x * 64;
  int px0 = blockIdx.y * 64;
  int z = blockIdx.z;
  int n = z / KSPLIT, ks = z % KSPLIT;
  int KK = KH*KH;
  int k0 = ks * Kchunk;
  int r   = tid >> 4;          // 0..15
  int col = (tid & 15) << 2;   // 0..60
  const float* inn = in + (size_t)n*FCc*PIX;
  int yb[4], xb[4];
  #pragma unroll
  for (int i = 0; i < 4; ++i) {
    int p = px0 + col + i;
    yb[i] = p / FWw; xb[i] = p - yb[i]*FWw;
  }
  float acc[4][4] = {};
  int steps = Kchunk >> 4;
  for (int s = 0; s < steps; ++s) {
    int kbase = k0 + (s << 4);
    float4 av = *(const float4*)&wT[(size_t)(kbase + r)*Mpad + oc0 + col];
    *(float4*)&la[r][col] = av;
    int k = kbase + r;
    int ic = k / KK;
    int rr = k - ic*KK;
    int ky = rr / KH, kx = rr - ky*KH;
    const float* ip = inn + (size_t)ic*PIX;
    #pragma unroll
    for (int i = 0; i < 4; ++i) {
      int yy = yb[i] + ky - PAD, xx = xb[i] + kx - PAD;
      float v = 0.f;
      if ((unsigned)yy < FHh && (unsigned)xx < FWw) v = ip[yy*FWw + xx];
      lb[r][col + i] = v;
    }
    __syncthreads();
    #pragma unroll
    for (int kk = 0; kk < 16; ++kk) {
      float4 a4 = *(const float4*)&la[kk][r << 2];
      float4 b4 = *(const float4*)&lb[kk][col];
      acc[0][0] += a4.x*b4.x; acc[0][1] += a4.x*b4.y; acc[0][2] += a4.x*b4.z; acc[0][3] += a4.x*b4.w;
      acc[1][0] += a4.y*b4.x; acc[1][1] += a4.y*b4.y; acc[1][2] += a4.y*b4.z; acc[1][3] += a4.y*b4.w;
      acc[2][0] += a4.z*b4.x; acc[2][1] += a4.z*b4.y; acc[2][2] += a4.z*b4.z; acc[2][3] += a4.z*b4.w;
      acc[3][0] += a4.w*b4.x; acc[3][1] += a4.w*b4.y; acc[3][2] += a4.w*b4.z; acc[3][3] += a4.w*b4.w;
    }
    __syncthreads();
  }
  if (bias) {
    #pragma unroll
    for (int i = 0; i < 4; ++i) {
      int oc = oc0 + (r<<2) + i;
      if (oc < oc_limit) {
        float b = bias[oc];
        float4 st = make_float4(acc[i][0]+b, acc[i][1]+b, acc[i][2]+b, acc[i][3]+b);
        *(float4*)&outbuf[(size_t)(n*oc_limit + oc)*PIX + px0 + col] = st;
      }
    }
  } else {
    float* pp = part + (size_t)(ks*NCAM + n)*Mpad*PIX;
    #pragma unroll
    for (int i = 0; i < 4; ++i) {
      float4 st = make_float4(acc[i][0], acc[i][1], acc[i][2], acc[i][3]);
      *(float4*)&pp[(size_t)(oc0 + (r<<2) + i)*PIX + px0 + col] = st;
    }
  }
}

__global__ void k_epi_bn(const float* __restrict__ part, const float* __restrict__ cb,
                         const float* __restrict__ g, const float* __restrict__ be,
                         const float* __restrict__ mn, const float* __restrict__ vr,
                         float* __restrict__ out, int KSPLIT)
{
  int idx = blockIdx.x*256 + threadIdx.x;       // float4 over [6][128][176]
  if (idx >= NCAM*FCc*176) return;
  int px4 = idx % 176;
  int t = idx / 176;
  int oc = t % FCc;
  int n = t / FCc;
  float4 s = {0.f,0.f,0.f,0.f};
  for (int ks = 0; ks < KSPLIT; ++ks) {
    const float4* p = (const float4*)(part + (size_t)((ks*NCAM+n)*FCc + oc)*PIX);
    float4 v = p[px4];
    s.x += v.x; s.y += v.y; s.z += v.z; s.w += v.w;
  }
  float inv = g[oc] * rsqrtf(vr[oc] + 1e-3f);
  float sh = (cb[oc] - mn[oc]) * inv + be[oc];
  float4 o;
  o.x = fmaxf(s.x*inv + sh, 0.f);
  o.y = fmaxf(s.y*inv + sh, 0.f);
  o.z = fmaxf(s.z*inv + sh, 0.f);
  o.w = fmaxf(s.w*inv + sh, 0.f);
  ((float4*)(out + (size_t)(n*FCc + oc)*PIX))[px4] = o;
}

// one wave per gaussian: softmax over depth, moments, raster params, feat transpose
__global__ void k_moments(float* __restrict__ ws) {
  int wid  = (blockIdx.x * 256 + threadIdx.x) >> 6;
  int lane = threadIdx.x & 63;
  int n = wid / PIX, hw = wid % PIX;
  const float* x3 = ws + OFF_X3 + (size_t)n*C3*PIX + hw;
  float logit = (lane < DB) ? x3[(size_t)lane*PIX] : -1e30f;
  float mx = logit;
  for (int off = 1; off < 64; off <<= 1) mx = fmaxf(mx, __shfl_xor(mx, off));
  float e = (lane < DB) ? expf(logit - mx) : 0.f;
  float s = e;
  for (int off = 1; off < 64; off <<= 1) s += __shfl_xor(s, off);
  float p = e / s;
  float gx = 0.f, gy = 0.f;
  if (lane < DB) {
    float2 g2 = ((const float2*)(ws + OFF_GEO))[(size_t)(n*DB + lane)*PIX + hw];
    gx = g2.x; gy = g2.y;
  }
  float sx = p*gx;
  for (int off = 1; off < 64; off <<= 1) sx += __shfl_xor(sx, off);
  float sy = p*gy;
  for (int off = 1; off < 64; off <<= 1) sy += __shfl_xor(sy, off);
  float dx = gx - sx, dy = gy - sy;
  float c00 = p*dx*dx, c01 = p*dx*dy, c11 = p*dy*dy;
  for (int off = 1; off < 64; off <<= 1) c00 += __shfl_xor(c00, off);
  for (int off = 1; off < 64; off <<= 1) c01 += __shfl_xor(c01, off);
  for (int off = 1; off < 64; off <<= 1) c11 += __shfl_xor(c11, off);
  float opl = x3[(size_t)DB*PIX];
  float opac = 1.f / (1.f + expf(-opl));
  // cov*(1/9) * scale^2(4e-4) * (sh*sw = 2500) => cov/9 in BEV cells, +0.3 dilate
  float a = c11*(1.f/9.f) + 0.3f;   // var along py
  float b = c01*(1.f/9.f);
  float c = c00*(1.f/9.f) + 0.3f;   // var along px
  float py = 50.f - sy;
  float px = 50.f - sx;
  float det = a*c - b*b;
  float op = (opac > 0.05f) ? opac : 0.f;
  float invd = 1.f;
  if (det > 0.f) invd = 1.f/det; else op = 0.f;
  float* prm = ws + OFF_PRM;
  if (lane == 0) {
    prm[0*NG + wid] = py;
    prm[1*NG + wid] = px;
    prm[2*NG + wid] = -0.5f*c*invd;  // dy^2 coeff
    prm[3*NG + wid] = -0.5f*a*invd;  // dx^2 coeff
    prm[4*NG + wid] = b*invd;        // dy*dx coeff
    prm[5*NG + wid] = op;
  }
  float* ft = ws + OFF_FEATT + (size_t)wid*128;
  ft[lane]      = x3[(size_t)(DB + 1 + lane)*PIX];
  ft[lane + 64] = x3[(size_t)(DB + 1 + lane + 64)*PIX];
}

// Dense barrier-free raster: one wave = one BEV pixel, scans all 66 groups of
// 64 Gaussians in index order. Coalesced SoA param loads prefetched one group
// ahead in registers; no LDS, no barriers -> waves retire independently.
// Per-wave early exit at T<1e-7; zero-hit groups skip everything.
__global__ __launch_bounds__(512) void k_raster(const float* __restrict__ ws,
                                                float* __restrict__ out) {
  int lane = threadIdx.x & 63, wv = threadIdx.x >> 6;
  int pix = blockIdx.x * 8 + wv;
  float yi = (float)(pix / 100), xi = (float)(pix % 100);
  const float* prm = ws + OFF_PRM;
  const float2* ft = (const float2*)(ws + OFF_FEATT);
  float T = 1.f, ax = 0.f, ay = 0.f;
  // preload group 0 (coalesced: lane i reads element g0+i of each SoA array)
  float c_py = prm[0*NG + lane], c_px = prm[1*NG + lane];
  float c_qc = prm[2*NG + lane], c_qa = prm[3*NG + lane];
  float c_qb = prm[4*NG + lane], c_op = prm[5*NG + lane];
  for (int g0 = 0; g0 < NG; g0 += 64) {
    // prefetch next group
    float n_py = 0.f, n_px = 0.f, n_qc = 0.f, n_qa = 0.f, n_qb = 0.f, n_op = 0.f;
    if (g0 + 64 < NG) {
      int nx = g0 + 64 + lane;
      n_py = prm[0*NG + nx]; n_px = prm[1*NG + nx];
      n_qc = prm[2*NG + nx]; n_qa = prm[3*NG + nx];
      n_qb = prm[4*NG + nx]; n_op = prm[5*NG + nx];
    }
    float dyv = c_py - yi, dxv = c_px - xi;
    float pw = c_qc*dyv*dyv + c_qa*dxv*dxv + c_qb*dyv*dxv;
    float alpha = c_op * __expf(fminf(pw, 0.f));
    alpha = fminf(alpha, 0.99f);
    if (alpha < (1.f/255.f)) alpha = 0.f;
    unsigned long long m0 = __ballot(alpha > 0.f);
    if (m0) {                          // wave-uniform fast-skip
      float P = 1.f - alpha;
      #pragma unroll
      for (int off = 1; off < 64; off <<= 1) {
        float v = __shfl_up(P, off);
        if (lane >= off) P *= v;
      }
      float E = __shfl_up(P, 1);
      if (lane == 0) E = 1.f;
      float w = alpha * T * E;         // alpha * exclusive transmittance
      T *= __shfl(P, 63);
      unsigned long long mask = __ballot(w > 1e-9f);
      while (mask) {
        int j = __builtin_ctzll(mask);
        mask &= mask - 1;
        float wj = __shfl(w, j);
        float2 f = ft[(size_t)(g0 + j)*64 + lane];
        ax += wj * f.x; ay += wj * f.y;
      }
      if (T < 1e-7f) break;            // wave-local exit (error < 1e-7)
    }
    c_py = n_py; c_px = n_px; c_qc = n_qc;
    c_qa = n_qa; c_qb = n_qb; c_op = n_op;
  }
  out[(size_t)(2*lane)*BEVN + pix]   = ax;
  out[(size_t)(2*lane+1)*BEVN + pix] = ay;
}

extern "C" void kernel_launch(void* const* d_in, const int* in_sizes, int n_in,
                              void* d_out, int out_size, void* d_ws, size_t ws_size,
                              hipStream_t stream) {
  const float* rot        = (const float*)d_in[0];
  const float* trans      = (const float*)d_in[1];
  const float* intr       = (const float*)d_in[2];
  const float* post_rot   = (const float*)d_in[3];
  const float* post_trans = (const float*)d_in[4];
  const float* img        = (const float*)d_in[5];
  const float* w1  = (const float*)d_in[6];
  const float* b1  = (const float*)d_in[7];
  const float* g1  = (const float*)d_in[8];
  const float* be1 = (const float*)d_in[9];
  const float* m1  = (const float*)d_in[10];
  const float* v1  = (const float*)d_in[11];
  const float* w2  = (const float*)d_in[12];
  const float* b2  = (const float*)d_in[13];
  const float* g2  = (const float*)d_in[14];
  const float* be2 = (const float*)d_in[15];
  const float* m2  = (const float*)d_in[16];
  const float* v2  = (const float*)d_in[17];
  const float* w3  = (const float*)d_in[18];
  const float* b3  = (const float*)d_in[19];
  float* ws  = (float*)d_ws;
  float* out = (float*)d_out;

  k_wtrans<<<576, 256, 0, stream>>>(w1, w2, w3, ws);
  k_geom<<<792, 256, 0, stream>>>(rot, intr, post_rot, trans, post_trans, ws);

  // conv1: K=1152, KSPLIT=4
  k_gemm<<<dim3(2,11,24), 256, 0, stream>>>(img, ws+OFF_WT1, ws+OFF_PART,
                                            nullptr, nullptr, 0, 128, 3, 1, 4, 288);
  k_epi_bn<<<528, 256, 0, stream>>>(ws+OFF_PART, b1, g1, be1, m1, v1, ws+OFF_X1, 4);
  // conv2
  k_gemm<<<dim3(2,11,24), 256, 0, stream>>>(ws+OFF_X1, ws+OFF_WT2, ws+OFF_PART,
                                            nullptr, nullptr, 0, 128, 3, 1, 4, 288);
  k_epi_bn<<<528, 256, 0, stream>>>(ws+OFF_PART, b2, g2, be2, m2, v2, ws+OFF_X2, 4);
  // conv3: 1x1, K=128, bias fused, direct write to X3
  k_gemm<<<dim3(3,11,6), 256, 0, stream>>>(ws+OFF_X2, ws+OFF_WT3, ws+OFF_PART,
                                           b3, ws+OFF_X3, C3, 192, 1, 0, 1, 128);

  k_moments<<<1056, 256, 0, stream>>>(ws);
  k_raster<<<1250, 512, 0, stream>>>(ws, out);
}